// Round 8
// baseline (234.747 us; speedup 1.0000x reference)
//
#include <hip/hip_runtime.h>
#include <hip/hip_bf16.h>

// ---------------------------------------------------------------------------
// PerWellMLPTransition on MI355X — round 8 (identical resubmission of round 7;
// rounds 6/7 were infra failures, never executed on hardware).
//
//   zt1[b,i] = sum_{jp,k} w[b,jp]*hz[b,k]*G[jp,k,i] + sum_{jp} w[b,jp]*Gb[jp,i]
//   All big contractions (transition GEMM, per-well heads) on MFMA with
//   hi/lo-split bf16 operands.
//
// Changes vs round 5 (counter-driven):
//  - prep: G-pack in 4 passes over a 32x132 tile; head-pack direct from global
//    -> union LDS 67.6KB -> 17KB -> ~5 blocks/CU (was 2, VALUBusy 33%).
//  - heads: zua staging deleted (A-frags built from zuf directly)
//    -> LDS 113.7KB -> 72.7KB; __launch_bounds__(512,4) so 2 blocks/CU is real.
// ---------------------------------------------------------------------------

#define NB   4096
#define LAT  128
#define UD   24
#define HIDN 200
#define ZUD  152
#define JPD  152

// ws layout (float units)
#define GT_OFF      0u          // frag-ordered G hi/lo bf16 (152*4096 chunks * 16B)
#define GB_OFF      2490368u    // [152][128] f32
#define HZ_OFF      2509824u    // [4096][128] f32
#define PART_OFF    3034112u    // [8][4096][128] f32
#define PART_STRIDE 524288u
#define WH1P_OFF    7228416u    // 16*2560 chunks * 16B
#define WH2P_OFF    7392256u    // 16*1024 chunks * 16B
#define WH3P_OFF    7457792u    // 16*256 chunks * 16B

typedef __attribute__((ext_vector_type(8))) short short8_t;
typedef __attribute__((ext_vector_type(4))) float f32x4;

union FragU { short8_t s; unsigned short u[8]; };
union Frag2 { short8_t s; __hip_bfloat162 h2[4]; };

__device__ __forceinline__ unsigned short bf16_rne(float x) {
  const unsigned u = __float_as_uint(x);
  return (unsigned short)((u + 0x7FFFu + ((u >> 16) & 1u)) >> 16);
}
__device__ __forceinline__ unsigned short bf16_hi(float x) {
  return (unsigned short)(__float_as_uint(x) >> 16);
}
__device__ __forceinline__ unsigned short bf16_lo(float x) {
  const float hif = __uint_as_float(__float_as_uint(x) & 0xFFFF0000u);
  return bf16_rne(x - hif);
}

#define MFMA_BF16(A, B, C) __builtin_amdgcn_mfma_f32_16x16x32_bf16((A), (B), (C), 0, 0, 0)

// ---------- kernel 1: prep = {G pack | encoder | head-weight pack} ----------
// blocks [0,152): G;  [152,664): encoder;  [664,680): head h weight pack.
__global__ __launch_bounds__(256, 5)
void prep_kernel(const float* __restrict__ WA, const float* __restrict__ bA,
                 const float* __restrict__ WB, const float* __restrict__ bB,
                 unsigned short* __restrict__ GtU, float* __restrict__ Gb,
                 const float* __restrict__ zt, const float* __restrict__ dt,
                 const float* __restrict__ We1, const float* __restrict__ be1,
                 const float* __restrict__ We2, const float* __restrict__ be2,
                 const float* __restrict__ We3, const float* __restrict__ be3,
                 float* __restrict__ hz,
                 const float* __restrict__ Wh1, const float* __restrict__ Wh2,
                 const float* __restrict__ Wh3,
                 short8_t* __restrict__ WH1P, short8_t* __restrict__ WH2P,
                 short8_t* __restrict__ WH3P) {
  __shared__ union {
    float tile32[32][132];                                           // G-pack pass tile
    struct { float xs[8][132]; float h1[8][200]; float h2[8][200]; } e;  // encoder
  } sh;
  const int t = threadIdx.x;

  if (blockIdx.x < 152) {
    // ---------------- G packing (4 passes of 32 output-cols) ----------------
    const int jp = blockIdx.x;
    const bool isA = (jp < LAT);
    const float* __restrict__ src = isA ? WA : WB;
    const int mul = isA ? LAT : UD;
    const int sub = isA ? jp : (jp - LAT);
    short8_t* __restrict__ G8 = (short8_t*)GtU;

    if (t < 128) {
      const float* __restrict__ bsrc = isA ? bA : bB;
      Gb[(jp << 7) + t] = bsrc[t * mul + sub];
    }

    for (int p = 0; p < 4; ++p) {
      for (int idx = t; idx < 1024; idx += 256) {      // 32 rows x 32 float4
        const int i = idx >> 5, c4 = (idx & 31) << 2;
        *(float4*)(&sh.tile32[i][c4]) =
            *(const float4*)(src + (size_t)(((p << 5) + i) * mul + sub) * 128 + c4);
      }
      __syncthreads();
#pragma unroll
      for (int q = 0; q < 4; ++q) {                    // 1024 chunks/pass
        const int cc  = (q << 8) + t;
        const int l   = cc & 63;
        const int spl = (cc >> 6) & 1;
        const int nloc = (cc >> 7) & 1;                // n = 2p + nloc
        const int ksq  = (cc >> 8) & 3;
        const int n    = (p << 1) + nloc;
        const int icl  = (nloc << 4) + (l & 15);       // local col in tile32
        const int k0   = (ksq << 5) + ((l >> 4) << 3);
        FragU fr;
#pragma unroll
        for (int j = 0; j < 8; ++j) {
          const float g = sh.tile32[icl][k0 + j];
          fr.u[j] = spl ? bf16_lo(g) : bf16_hi(g);
        }
        const int c = ((((ksq << 3) + n) << 1) + spl) * 64 + l;
        G8[(size_t)jp * 4096 + c] = fr.s;
      }
      __syncthreads();
    }
    return;
  }

  if (blockIdx.x >= 664) {
    // ---------------- head-weight packing (direct from global, no LDS) ----------------
    const int h = blockIdx.x - 664;
    for (int c = t; c < 2560; c += 256) {              // Wh1: K padded 152->160
      const int l = c & 63, spl = (c >> 6) & 1, nt = (c >> 7) & 3, ks = c >> 9;
      const int col = (nt << 4) + (l & 15);
      const int k0  = (ks << 5) + ((l >> 4) << 3);
      const float* __restrict__ wr = Wh1 + ((size_t)h * 64 + col) * ZUD;
      FragU fr;
#pragma unroll
      for (int j = 0; j < 8; ++j) {
        const int k = k0 + j;
        const float v = (k < ZUD) ? wr[k] : 0.f;
        fr.u[j] = spl ? bf16_lo(v) : bf16_hi(v);
      }
      WH1P[(size_t)h * 2560 + c] = fr.s;
    }
    for (int c = t; c < 1024; c += 256) {              // Wh2: K=64
      const int l = c & 63, spl = (c >> 6) & 1, nt = (c >> 7) & 3, ks = (c >> 9) & 1;
      const int col = (nt << 4) + (l & 15);
      const int k0  = (ks << 5) + ((l >> 4) << 3);
      const float* __restrict__ wr = Wh2 + ((size_t)h * 64 + col) * 64 + k0;
      FragU fr;
#pragma unroll
      for (int j = 0; j < 8; ++j) {
        const float v = wr[j];
        fr.u[j] = spl ? bf16_lo(v) : bf16_hi(v);
      }
      WH2P[(size_t)h * 1024 + c] = fr.s;
    }
    for (int c = t; c < 256; c += 256) {               // Wh3: K=64, cols>=2 zero
      const int l = c & 63, spl = (c >> 6) & 1, ks = (c >> 7) & 1;
      const int col = l & 15;
      const int k0  = (ks << 5) + ((l >> 4) << 3);
      FragU fr;
#pragma unroll
      for (int j = 0; j < 8; ++j) {
        const float v = (col < 2) ? Wh3[((size_t)h * 2 + col) * 64 + k0 + j] : 0.f;
        fr.u[j] = spl ? bf16_lo(v) : bf16_hi(v);
      }
      WH3P[(size_t)h * 256 + c] = fr.s;
    }
    return;
  }

  // ---------------- encoder ----------------
  const int b0 = (blockIdx.x - 152) * 8;

  for (int idx = t; idx < 8 * 129; idx += 256) {
    const int r = idx / 129, c = idx - r * 129;
    sh.e.xs[r][c] = (c < LAT) ? zt[(size_t)(b0 + r) * LAT + c] : dt[b0 + r];
  }
  __syncthreads();

  if (t < HIDN) {
    const float* __restrict__ w = We1 + t * 129;
    float acc[8];
    const float bias = be1[t];
#pragma unroll
    for (int r = 0; r < 8; ++r) acc[r] = bias;
    for (int c = 0; c < 128; c += 4) {
      const float w0 = w[c], w1 = w[c + 1], w2 = w[c + 2], w3 = w[c + 3];
#pragma unroll
      for (int r = 0; r < 8; ++r) {
        const float4 xv = *(const float4*)(&sh.e.xs[r][c]);
        acc[r] += xv.x * w0 + xv.y * w1 + xv.z * w2 + xv.w * w3;
      }
    }
    const float wl = w[128];
#pragma unroll
    for (int r = 0; r < 8; ++r) sh.e.h1[r][t] = fmaxf(fmaf(sh.e.xs[r][128], wl, acc[r]), 0.f);
  }
  __syncthreads();

  if (t < HIDN) {
    const float* __restrict__ w = We2 + t * HIDN;
    float acc[8];
    const float bias = be2[t];
#pragma unroll
    for (int r = 0; r < 8; ++r) acc[r] = bias;
    for (int c = 0; c < HIDN; c += 4) {
      const float4 wv = *(const float4*)(w + c);
#pragma unroll
      for (int r = 0; r < 8; ++r) {
        const float4 hv = *(const float4*)(&sh.e.h1[r][c]);
        acc[r] += hv.x * wv.x + hv.y * wv.y + hv.z * wv.z + hv.w * wv.w;
      }
    }
#pragma unroll
    for (int r = 0; r < 8; ++r) sh.e.h2[r][t] = fmaxf(acc[r], 0.f);
  }
  __syncthreads();

  if (t < LAT) {
    const float* __restrict__ w = We3 + t * HIDN;
    float acc[8];
    const float bias = be3[t];
#pragma unroll
    for (int r = 0; r < 8; ++r) acc[r] = bias;
    for (int c = 0; c < HIDN; c += 4) {
      const float4 wv = *(const float4*)(w + c);
#pragma unroll
      for (int r = 0; r < 8; ++r) {
        const float4 hv = *(const float4*)(&sh.e.h2[r][c]);
        acc[r] += hv.x * wv.x + hv.y * wv.y + hv.z * wv.z + hv.w * wv.w;
      }
    }
#pragma unroll
    for (int r = 0; r < 8; ++r) hz[(size_t)(b0 + r) * LAT + t] = acc[r];
  }
}

// ---------- kernel 2: MFMA transition GEMM (unchanged) ----------
#define GBODY(JP, B00, B01, B10, B11, NJP)                                      \
  {                                                                             \
    const int jp_ = (JP);                                                       \
    const float w0_ = wtile[(rw << 5) + lr][jp_];                               \
    const float w1_ = wtile[(rw << 5) + 16 + lr][jp_];                          \
    Frag2 p0_, p1_;                                                             \
    _Pragma("unroll")                                                           \
    for (int jq = 0; jq < 4; ++jq) {                                            \
      p0_.h2[jq] = __float22bfloat162_rn(                                       \
          make_float2(w0_ * hzr0[2 * jq], w0_ * hzr0[2 * jq + 1]));             \
      p1_.h2[jq] = __float22bfloat162_rn(                                       \
          make_float2(w1_ * hzr1[2 * jq], w1_ * hzr1[2 * jq + 1]));             \
    }                                                                           \
    acc00 = MFMA_BF16(p0_.s, B00, acc00);                                       \
    acc00 = MFMA_BF16(p0_.s, B01, acc00);                                       \
    acc01 = MFMA_BF16(p0_.s, B10, acc01);                                       \
    acc01 = MFMA_BF16(p0_.s, B11, acc01);                                       \
    acc10 = MFMA_BF16(p1_.s, B00, acc10);                                       \
    acc10 = MFMA_BF16(p1_.s, B01, acc10);                                       \
    acc11 = MFMA_BF16(p1_.s, B10, acc11);                                       \
    acc11 = MFMA_BF16(p1_.s, B11, acc11);                                       \
    const size_t nb_ = (size_t)(NJP) * 4096;                                    \
    B00 = G8[nb_ + c00]; B01 = G8[nb_ + c01];                                   \
    B10 = G8[nb_ + c10]; B11 = G8[nb_ + c11];                                   \
  }

__global__ __launch_bounds__(512, 4)
void gemm_mfma_kernel(const float* __restrict__ zt, const float* __restrict__ dt,
                      const float* __restrict__ ut,
                      const unsigned short* __restrict__ GtU,
                      const float* __restrict__ Gb,
                      const float* __restrict__ hz, float* __restrict__ part) {
  __shared__ float wtile[64][156];
  const int t  = threadIdx.x;
  const int l  = t & 63;
  const int w  = t >> 6;
  const int rw = w & 1, cw = w >> 1;
  const int bid   = blockIdx.x;
  const int combo = bid & 7;
  const int ks    = combo & 3;
  const int jph   = combo >> 2;
  const int b0    = (bid >> 3) << 6;
  const int lr  = l & 15, lg = l >> 4;
  const int j0  = jph * 76;

  for (int idx = t; idx < 2048; idx += 512) {
    const int r = idx >> 5, c4 = (idx & 31) << 2;
    *(float4*)(&wtile[r][c4]) = *(const float4*)(zt + (((size_t)(b0 + r)) << 7) + c4);
  }
  for (int idx = t; idx < 384; idx += 512) {
    const int r = idx / 6, u4 = (idx - r * 6) << 2;
    float4 v = *(const float4*)(ut + (size_t)(b0 + r) * UD + u4);
    const float s = dt[b0 + r];
    v.x *= s; v.y *= s; v.z *= s; v.w *= s;
    *(float4*)(&wtile[r][LAT + u4]) = v;
  }
  __syncthreads();

  const int kk = (ks << 5) + (lg << 3);
  float hzr0[8], hzr1[8];
  {
    const float* __restrict__ hp0 = hz + (((size_t)(b0 + (rw << 5) + lr)) << 7) + kk;
    const float* __restrict__ hp1 = hz + (((size_t)(b0 + (rw << 5) + 16 + lr)) << 7) + kk;
    const float4 a0 = *(const float4*)hp0, b0v = *(const float4*)(hp0 + 4);
    const float4 a1 = *(const float4*)hp1, b1v = *(const float4*)(hp1 + 4);
    hzr0[0]=a0.x; hzr0[1]=a0.y; hzr0[2]=a0.z; hzr0[3]=a0.w;
    hzr0[4]=b0v.x; hzr0[5]=b0v.y; hzr0[6]=b0v.z; hzr0[7]=b0v.w;
    hzr1[0]=a1.x; hzr1[1]=a1.y; hzr1[2]=a1.z; hzr1[3]=a1.w;
    hzr1[4]=b1v.x; hzr1[5]=b1v.y; hzr1[6]=b1v.z; hzr1[7]=b1v.w;
  }

  const short8_t* __restrict__ G8 = (const short8_t*)GtU;
  const int n0 = (cw << 1), n1 = (cw << 1) + 1;
  const int c00 = ((((ks << 3) + n0) << 1) + 0) * 64 + l;
  const int c01 = ((((ks << 3) + n0) << 1) + 1) * 64 + l;
  const int c10 = ((((ks << 3) + n1) << 1) + 0) * 64 + l;
  const int c11 = ((((ks << 3) + n1) << 1) + 1) * 64 + l;

  f32x4 acc00 = {0.f,0.f,0.f,0.f}, acc01 = {0.f,0.f,0.f,0.f};
  f32x4 acc10 = {0.f,0.f,0.f,0.f}, acc11 = {0.f,0.f,0.f,0.f};

  short8_t A0 = G8[(size_t)(j0+0)*4096 + c00], A1 = G8[(size_t)(j0+0)*4096 + c01],
           A2 = G8[(size_t)(j0+0)*4096 + c10], A3 = G8[(size_t)(j0+0)*4096 + c11];
  short8_t Bv0 = G8[(size_t)(j0+1)*4096 + c00], Bv1 = G8[(size_t)(j0+1)*4096 + c01],
           Bv2 = G8[(size_t)(j0+1)*4096 + c10], Bv3 = G8[(size_t)(j0+1)*4096 + c11];
  short8_t C0 = G8[(size_t)(j0+2)*4096 + c00], C1 = G8[(size_t)(j0+2)*4096 + c01],
           C2 = G8[(size_t)(j0+2)*4096 + c10], C3 = G8[(size_t)(j0+2)*4096 + c11];
  short8_t D0 = G8[(size_t)(j0+3)*4096 + c00], D1 = G8[(size_t)(j0+3)*4096 + c01],
           D2 = G8[(size_t)(j0+3)*4096 + c10], D3 = G8[(size_t)(j0+3)*4096 + c11];

  const int jend = j0 + 76;
  for (int jp = j0; jp < jend; jp += 4) {
    const int n4 = (jp + 4 < jend) ? jp + 4 : jend - 1;
    const int n5 = (jp + 5 < jend) ? jp + 5 : jend - 1;
    const int n6 = (jp + 6 < jend) ? jp + 6 : jend - 1;
    const int n7 = (jp + 7 < jend) ? jp + 7 : jend - 1;
    GBODY(jp + 0, A0, A1, A2, A3, n4);
    GBODY(jp + 1, Bv0, Bv1, Bv2, Bv3, n5);
    GBODY(jp + 2, C0, C1, C2, C3, n6);
    GBODY(jp + 3, D0, D1, D2, D3, n7);
  }

  {
    const int jb0 = combo * 19;
    for (int jp = jb0; jp < jb0 + 19; ++jp) {
      const float gb0 = Gb[(jp << 7) + (cw << 5) + lr];
      const float gb1 = Gb[(jp << 7) + (cw << 5) + 16 + lr];
#pragma unroll
      for (int r = 0; r < 4; ++r) {
        const float wv0 = wtile[(rw << 5) + (lg << 2) + r][jp];
        const float wv1 = wtile[(rw << 5) + 16 + (lg << 2) + r][jp];
        acc00[r] += wv0 * gb0; acc01[r] += wv0 * gb1;
        acc10[r] += wv1 * gb0; acc11[r] += wv1 * gb1;
      }
    }
  }

  float* __restrict__ dst = part + (size_t)combo * PART_STRIDE + (((size_t)b0) << 7);
  const int colb = (cw << 5) + lr;
#pragma unroll
  for (int r = 0; r < 4; ++r) {
    const int row0 = (rw << 5) + (lg << 2) + r;
    const int row1 = row0 + 16;
    dst[((size_t)row0 << 7) + colb]      = acc00[r];
    dst[((size_t)row0 << 7) + colb + 16] = acc01[r];
    dst[((size_t)row1 << 7) + colb]      = acc10[r];
    dst[((size_t)row1 << 7) + colb + 16] = acc11[r];
  }
}

// ---------- kernel 3: MFMA heads ----------
// grid 256 = (mb 0..63) x (hg 0..3). Block: rows b0=mb*64, heads hg*4..+4.
// 512 thr = 8 waves: wm = w>>1 (16-row m-tile), wn = w&1 (32-col n-half).
// LDS 72.7KB + launch_bounds(512,4) -> 2 blocks/CU.
__global__ __launch_bounds__(512, 4)
void heads_kernel(const float* __restrict__ ut, const float* __restrict__ part,
                  const short8_t* __restrict__ WH1P, const float* __restrict__ bh1,
                  const short8_t* __restrict__ WH2P, const float* __restrict__ bh2,
                  const short8_t* __restrict__ WH3P, const float* __restrict__ bh3,
                  const float* __restrict__ Wi, const float* __restrict__ bi,
                  float* __restrict__ out) {
  __shared__ float    zuf[64][156];    // f32 zu (reduce staging + injector + frag source)
  __shared__ short8_t g1a[1024];       // g1 A-frags: [mt4][ks2][spl2][l64]
  __shared__ short8_t g2a[1024];       // g2 A-frags: same shape
  const int t  = threadIdx.x;
  const int l  = t & 63;
  const int w  = t >> 6;
  const int wm = w >> 1, wn = w & 1;
  const int mb = blockIdx.x >> 2;
  const int hg = blockIdx.x & 3;
  const int b0 = mb << 6;
  float* __restrict__ zt1_out = out;
  float* __restrict__ yt1_out = out + (size_t)NB * LAT;

  // ---- phase 0: reduce 8 partial slices -> zuf rows; hg0 writes zt1 ----
  for (int idx = t; idx < 2048; idx += 512) {         // 64 rows x 32 float4
    const int r = idx >> 5, c4 = (idx & 31) << 2;
    const size_t off = (((size_t)(b0 + r)) << 7) + c4;
    float4 s = *(const float4*)(part + off);
#pragma unroll
    for (int q = 1; q < 8; ++q) {
      const float4 v = *(const float4*)(part + (size_t)q * PART_STRIDE + off);
      s.x += v.x; s.y += v.y; s.z += v.z; s.w += v.w;
    }
    *(float4*)(&zuf[r][c4]) = s;
    if (hg == 0) *(float4*)(zt1_out + off) = s;
  }
  for (int idx = t; idx < 384; idx += 512) {          // ut -> cols 128..151
    const int r = idx / 6, u4 = (idx - r * 6) << 2;
    *(float4*)(&zuf[r][LAT + u4]) = *(const float4*)(ut + (size_t)(b0 + r) * UD + u4);
  }
  __syncthreads();

  // ---- zu A-frags built directly from zuf (head-invariant, per-lane) ----
  short8_t Ahi[5], Alo[5];
  {
    const int arow = (wm << 4) + (l & 15);
#pragma unroll
    for (int ks = 0; ks < 5; ++ks) {
      const int k0 = (ks << 5) + ((l >> 4) << 3);
      FragU fh, fl;
      if (k0 < ZUD) {                                 // k0 <= 144: full 8 valid
        const float4 va = *(const float4*)(&zuf[arow][k0]);
        const float4 vb = *(const float4*)(&zuf[arow][k0 + 4]);
        const float vv[8] = {va.x, va.y, va.z, va.w, vb.x, vb.y, vb.z, vb.w};
#pragma unroll
        for (int j = 0; j < 8; ++j) { fh.u[j] = bf16_hi(vv[j]); fl.u[j] = bf16_lo(vv[j]); }
      } else {                                        // k0 == 152: zero pad
#pragma unroll
        for (int j = 0; j < 8; ++j) { fh.u[j] = 0; fl.u[j] = 0; }
      }
      Ahi[ks] = fh.s; Alo[ks] = fl.s;
    }
  }

  unsigned short* __restrict__ g1s = (unsigned short*)g1a;
  unsigned short* __restrict__ g2s = (unsigned short*)g2a;
  const int lq = l >> 4;   // 0..3

  for (int hc = 0; hc < 4; ++hc) {
    const int hh = (hg << 2) + hc;

    // ---- layer 1: [64x160] x [160x64], 3-product hi/lo ----
    const short8_t* __restrict__ W1 = WH1P + (size_t)hh * 2560;
    short8_t b1h[5][2], b1l[5][2];
#pragma unroll
    for (int ks = 0; ks < 5; ++ks)
#pragma unroll
      for (int nt = 0; nt < 2; ++nt) {
        const int ntg = (wn << 1) + nt;
        b1h[ks][nt] = W1[(((ks << 2) + ntg) * 2 + 0) * 64 + l];
        b1l[ks][nt] = W1[(((ks << 2) + ntg) * 2 + 1) * 64 + l];
      }
    f32x4 a1[2] = {{0.f,0.f,0.f,0.f},{0.f,0.f,0.f,0.f}};
#pragma unroll
    for (int ks = 0; ks < 5; ++ks)
#pragma unroll
      for (int nt = 0; nt < 2; ++nt) {
        a1[nt] = MFMA_BF16(Ahi[ks], b1h[ks][nt], a1[nt]);
        a1[nt] = MFMA_BF16(Alo[ks], b1h[ks][nt], a1[nt]);
        a1[nt] = MFMA_BF16(Ahi[ks], b1l[ks][nt], a1[nt]);
      }
    // bias + relu + write A-frag-ordered g1
#pragma unroll
    for (int nt = 0; nt < 2; ++nt) {
      const int C = (wn << 5) + (nt << 4) + (l & 15);
      const float bv = bh1[(hh << 6) + C];
      const int chunkbase = (((wm << 1) + (C >> 5)) << 1);
#pragma unroll
      for (int r = 0; r < 4; ++r) {
        const float v = fmaxf(a1[nt][r] + bv, 0.f);
        const int lane2 = ((lq << 2) + r) | ((((C >> 3) & 3)) << 4);
        g1s[(((chunkbase + 0) * 64 + lane2) << 3) + (C & 7)] = bf16_hi(v);
        g1s[(((chunkbase + 1) * 64 + lane2) << 3) + (C & 7)] = bf16_lo(v);
      }
    }
    __syncthreads();

    // ---- layer 2: [64x64] x [64x64] ----
    const short8_t* __restrict__ W2 = WH2P + (size_t)hh * 1024;
    short8_t A2h[2], A2l[2];
#pragma unroll
    for (int ks = 0; ks < 2; ++ks) {
      A2h[ks] = g1a[(((wm << 1) + ks) * 2 + 0) * 64 + l];
      A2l[ks] = g1a[(((wm << 1) + ks) * 2 + 1) * 64 + l];
    }
    f32x4 a2[2] = {{0.f,0.f,0.f,0.f},{0.f,0.f,0.f,0.f}};
#pragma unroll
    for (int ks = 0; ks < 2; ++ks)
#pragma unroll
      for (int nt = 0; nt < 2; ++nt) {
        const int ntg = (wn << 1) + nt;
        const short8_t bh = W2[(((ks << 2) + ntg) * 2 + 0) * 64 + l];
        const short8_t bl = W2[(((ks << 2) + ntg) * 2 + 1) * 64 + l];
        a2[nt] = MFMA_BF16(A2h[ks], bh, a2[nt]);
        a2[nt] = MFMA_BF16(A2l[ks], bh, a2[nt]);
        a2[nt] = MFMA_BF16(A2h[ks], bl, a2[nt]);
      }
#pragma unroll
    for (int nt = 0; nt < 2; ++nt) {
      const int C = (wn << 5) + (nt << 4) + (l & 15);
      const float bv = bh2[(hh << 6) + C];
      const int chunkbase = (((wm << 1) + (C >> 5)) << 1);
#pragma unroll
      for (int r = 0; r < 4; ++r) {
        const float v = fmaxf(a2[nt][r] + bv, 0.f);
        const int lane2 = ((lq << 2) + r) | ((((C >> 3) & 3)) << 4);
        g2s[(((chunkbase + 0) * 64 + lane2) << 3) + (C & 7)] = bf16_hi(v);
        g2s[(((chunkbase + 1) * 64 + lane2) << 3) + (C & 7)] = bf16_lo(v);
      }
    }
    __syncthreads();

    // ---- layer 3: [64x64] x [64x16] (cols 0..1 valid), wn==0 waves only ----
    if (wn == 0) {
      const short8_t* __restrict__ W3 = WH3P + (size_t)hh * 256;
      f32x4 a3 = {0.f,0.f,0.f,0.f};
#pragma unroll
      for (int ks = 0; ks < 2; ++ks) {
        const short8_t Ah = g2a[(((wm << 1) + ks) * 2 + 0) * 64 + l];
        const short8_t Al = g2a[(((wm << 1) + ks) * 2 + 1) * 64 + l];
        const short8_t bh = W3[((ks << 1) + 0) * 64 + l];
        const short8_t bl = W3[((ks << 1) + 1) * 64 + l];
        a3 = MFMA_BF16(Ah, bh, a3);
        a3 = MFMA_BF16(Al, bh, a3);
        a3 = MFMA_BF16(Ah, bl, a3);
      }
      if ((l & 15) < 2) {
        const int col = l & 15;
        const float bv = bh3[(hh << 1) + col];
#pragma unroll
        for (int r = 0; r < 4; ++r) {
          const int R = (wm << 4) + (lq << 2) + r;
          yt1_out[(size_t)(b0 + R) * 40 + (hh << 1) + col] = a3[r] + bv;
        }
      }
    }
  }

  // ---- injector (hg3 blocks): inj = zu @ Wi.T + bi ----
  if (hg == 3) {
    const int r  = t >> 3, io = t & 7;
    const float4* __restrict__ wrow = (const float4*)(Wi + (size_t)io * ZUD);
    const float4* __restrict__ zr   = (const float4*)(&zuf[r][0]);
    float a0 = 0, a1 = 0, a2 = 0, a3 = 0;
#pragma unroll
    for (int cc = 0; cc < 38; ++cc) {
      const float4 wv = wrow[cc];
      const float4 zv = zr[cc];
      a0 = fmaf(wv.x, zv.x, a0); a1 = fmaf(wv.y, zv.y, a1);
      a2 = fmaf(wv.z, zv.z, a2); a3 = fmaf(wv.w, zv.w, a3);
    }
    yt1_out[(size_t)(b0 + r) * 40 + 32 + io] = a0 + a1 + a2 + a3 + bi[io];
  }
}

// ---------------------------------------------------------------------------
extern "C" void kernel_launch(void* const* d_in, const int* in_sizes, int n_in,
                              void* d_out, int out_size, void* d_ws, size_t ws_size,
                              hipStream_t stream) {
  const float* zt  = (const float*)d_in[0];
  const float* dt  = (const float*)d_in[1];
  const float* ut  = (const float*)d_in[2];
  const float* We1 = (const float*)d_in[3];
  const float* be1 = (const float*)d_in[4];
  const float* We2 = (const float*)d_in[5];
  const float* be2 = (const float*)d_in[6];
  const float* We3 = (const float*)d_in[7];
  const float* be3 = (const float*)d_in[8];
  const float* WA  = (const float*)d_in[9];
  const float* bA  = (const float*)d_in[10];
  const float* WB  = (const float*)d_in[11];
  const float* bB  = (const float*)d_in[12];
  const float* Wh1 = (const float*)d_in[13];
  const float* bh1 = (const float*)d_in[14];
  const float* Wh2 = (const float*)d_in[15];
  const float* bh2 = (const float*)d_in[16];
  const float* Wh3 = (const float*)d_in[17];
  const float* bh3 = (const float*)d_in[18];
  const float* Wi  = (const float*)d_in[19];
  const float* bi  = (const float*)d_in[20];

  float* ws = (float*)d_ws;
  unsigned short* GtU = (unsigned short*)(ws + GT_OFF);
  float* Gb   = ws + GB_OFF;
  float* hz   = ws + HZ_OFF;
  float* part = ws + PART_OFF;
  short8_t* WH1P = (short8_t*)(ws + WH1P_OFF);
  short8_t* WH2P = (short8_t*)(ws + WH2P_OFF);
  short8_t* WH3P = (short8_t*)(ws + WH3P_OFF);
  float* out  = (float*)d_out;

  hipLaunchKernelGGL(prep_kernel, dim3(152 + NB / 8 + 16), dim3(256), 0, stream,
                     WA, bA, WB, bB, GtU, Gb,
                     zt, dt, We1, be1, We2, be2, We3, be3, hz,
                     Wh1, Wh2, Wh3, WH1P, WH2P, WH3P);
  hipLaunchKernelGGL(gemm_mfma_kernel, dim3(512), dim3(512), 0, stream,
                     zt, dt, ut, GtU, Gb, hz, part);
  hipLaunchKernelGGL(heads_kernel, dim3(256), dim3(512), 0, stream,
                     ut, part, WH1P, bh1, WH2P, bh2, WH3P, bh3, Wi, bi, out);
}

// Round 11
// 197.832 us; speedup vs baseline: 1.1866x; 1.1866x over previous
//
#include <hip/hip_runtime.h>
#include <hip/hip_bf16.h>

// ---------------------------------------------------------------------------
// PerWellMLPTransition on MI355X — round 11 (identical resubmission of round 9;
// rounds 9/10 were infra failures — acquisition timeout / container failure —
// never executed. Round-6's identical "container failed twice" signature later
// passed unchanged in round 8, confirming infra-side cause.)
//
//   zt1[b,i] = sum_{jp,k} w[b,jp]*hz[b,k]*G[jp,k,i] + sum_{jp} w[b,jp]*Gb[jp,i]
//   ALL MLP contractions (encoder, transition GEMM, per-well heads) on MFMA
//   with hi/lo-split bf16 operands (3-product ~= f32 precision).
//
// vs round 8 (counter-driven): prep was 70us, VALUBusy 31% — encoder was
// L2/LDS-operand-sharing-bound (uncoalesced per-thread weight rows, 1.7M
// ds_read_b128). Encoder now MFMA (256 blocks x 16 rows); packing is one
// grid-stride streaming pass (no LDS, no syncs, coalesced fragment gathers).
// ---------------------------------------------------------------------------

#define NB   4096
#define LAT  128
#define UD   24
#define HIDN 200
#define ZUD  152
#define JPD  152

#define ENC_NB  256
#define PACK_NB 512

// ws layout (float units)
#define GT_OFF      0u          // frag-ordered G hi/lo bf16 (152*4096 chunks * 16B)
#define GB_OFF      2490368u    // [152][128] f32
#define HZ_OFF      2509824u    // [4096][128] f32
#define PART_OFF    3034112u    // [8][4096][128] f32
#define PART_STRIDE 524288u
#define WH1P_OFF    7228416u    // 16*2560 chunks * 16B
#define WH2P_OFF    7392256u    // 16*1024 chunks * 16B
#define WH3P_OFF    7457792u    // 16*256 chunks * 16B

typedef __attribute__((ext_vector_type(8))) short short8_t;
typedef __attribute__((ext_vector_type(4))) float f32x4;

union FragU { short8_t s; unsigned short u[8]; };
union Frag2 { short8_t s; __hip_bfloat162 h2[4]; };

__device__ __forceinline__ unsigned short bf16_rne(float x) {
  const unsigned u = __float_as_uint(x);
  return (unsigned short)((u + 0x7FFFu + ((u >> 16) & 1u)) >> 16);
}
__device__ __forceinline__ unsigned short bf16_hi(float x) {
  return (unsigned short)(__float_as_uint(x) >> 16);
}
__device__ __forceinline__ unsigned short bf16_lo(float x) {
  const float hif = __uint_as_float(__float_as_uint(x) & 0xFFFF0000u);
  return bf16_rne(x - hif);
}
// split 8 f32 -> hi frag (trunc) + lo frag (RNE residual, packed cvt)
__device__ __forceinline__ void build_hilo8(const float* vv, short8_t& hi, short8_t& lo) {
  FragU fh; Frag2 fl;
#pragma unroll
  for (int j = 0; j < 8; ++j) fh.u[j] = bf16_hi(vv[j]);
#pragma unroll
  for (int j = 0; j < 4; ++j) {
    const float d0 = vv[2*j]   - __uint_as_float(__float_as_uint(vv[2*j])   & 0xFFFF0000u);
    const float d1 = vv[2*j+1] - __uint_as_float(__float_as_uint(vv[2*j+1]) & 0xFFFF0000u);
    fl.h2[j] = __float22bfloat162_rn(make_float2(d0, d1));
  }
  hi = fh.s; lo = fl.s;
}

#define MFMA_BF16(A, B, C) __builtin_amdgcn_mfma_f32_16x16x32_bf16((A), (B), (C), 0, 0, 0)

// ---------- kernel 1: prep = {MFMA encoder | streaming pack} ----------
// blocks [0,256): encoder (16 rows each); [256,768): pack grid-stride.
__global__ __launch_bounds__(512, 4)
void prep_kernel(const float* __restrict__ WA, const float* __restrict__ bA,
                 const float* __restrict__ WB, const float* __restrict__ bB,
                 unsigned short* __restrict__ GtU, float* __restrict__ Gb,
                 const float* __restrict__ zt, const float* __restrict__ dt,
                 const float* __restrict__ We1, const float* __restrict__ be1,
                 const float* __restrict__ We2, const float* __restrict__ be2,
                 const float* __restrict__ We3, const float* __restrict__ be3,
                 float* __restrict__ hz,
                 const float* __restrict__ Wh1, const float* __restrict__ Wh2,
                 const float* __restrict__ Wh3,
                 short8_t* __restrict__ WH1P, short8_t* __restrict__ WH2P,
                 short8_t* __restrict__ WH3P) {
  __shared__ float bufA[16][260];   // xs (l1 in), then h2 (l3 in). pad 260 -> 2-way banks
  __shared__ float bufB[16][260];   // h1 (l2 in)
  const int t = threadIdx.x;

  if (blockIdx.x < ENC_NB) {
    // ================= MFMA encoder: 16 rows =================
    const int b0 = blockIdx.x << 4;
    // stage xs = [zt, dt, 0-pad] into bufA cols 0..159
    for (int idx = t; idx < 16 * 160; idx += 512) {
      const int r = idx / 160, c = idx - r * 160;
      float v = 0.f;
      if (c < LAT) v = zt[(size_t)(b0 + r) * LAT + c];
      else if (c == LAT) v = dt[b0 + r];
      bufA[r][c] = v;
    }
    if (t < 256) {                      // zero l2's K-pad region of h1
      bufB[t >> 4][208 + (t & 15)] = 0.f;
    }
    __syncthreads();

    const int w  = t >> 6;              // wave 0..7
    const int l  = t & 63;
    const int lr = l & 15, lg = l >> 4;
    const int kbase = lg << 3;

    // ---------- layer 1: [16x160] x We1[200x129] -> relu -> bufB ----------
    {
      short8_t Ah[5], Al[5];
#pragma unroll
      for (int kf = 0; kf < 5; ++kf) {
        float vv[8];
        const float* ap = &bufA[lr][(kf << 5) + kbase];
        *(float4*)(vv)     = *(const float4*)(ap);
        *(float4*)(vv + 4) = *(const float4*)(ap + 4);
        build_hilo8(vv, Ah[kf], Al[kf]);
      }
#pragma unroll
      for (int tt = 0; tt < 2; ++tt) {
        const int nt = w + (tt << 3);
        if (nt > 12) break;             // 13 n-tiles (N pad 208)
        const int col = (nt << 4) + lr;
        f32x4 acc = {0.f, 0.f, 0.f, 0.f};
#pragma unroll
        for (int kf = 0; kf < 5; ++kf) {
          const int k0 = (kf << 5) + kbase;
          float vv[8];
          if (col < HIDN) {
            const float* wp = We1 + (size_t)col * 129 + k0;
#pragma unroll
            for (int j = 0; j < 8; ++j) vv[j] = (k0 + j < 129) ? wp[j] : 0.f;
          } else {
#pragma unroll
            for (int j = 0; j < 8; ++j) vv[j] = 0.f;
          }
          short8_t Bh, Bl;
          build_hilo8(vv, Bh, Bl);
          acc = MFMA_BF16(Ah[kf], Bh, acc);
          acc = MFMA_BF16(Al[kf], Bh, acc);
          acc = MFMA_BF16(Ah[kf], Bl, acc);
        }
        const float bv = (col < HIDN) ? be1[col] : 0.f;
#pragma unroll
        for (int r = 0; r < 4; ++r)
          bufB[(lg << 2) + r][col] = fmaxf(acc[r] + bv, 0.f);
      }
    }
    __syncthreads();

    // ---------- layer 2: [16x224] x We2[200x200] -> relu -> bufA ----------
    {
      short8_t Ah[7], Al[7];
#pragma unroll
      for (int kf = 0; kf < 7; ++kf) {
        float vv[8];
        const float* ap = &bufB[lr][(kf << 5) + kbase];
        *(float4*)(vv)     = *(const float4*)(ap);
        *(float4*)(vv + 4) = *(const float4*)(ap + 4);
        build_hilo8(vv, Ah[kf], Al[kf]);
      }
#pragma unroll
      for (int tt = 0; tt < 2; ++tt) {
        const int nt = w + (tt << 3);
        if (nt > 13) break;             // 14 n-tiles (N pad 224; cols>=200 -> 0)
        const int col = (nt << 4) + lr;
        f32x4 acc = {0.f, 0.f, 0.f, 0.f};
#pragma unroll
        for (int kf = 0; kf < 7; ++kf) {
          const int k0 = (kf << 5) + kbase;
          float vv[8];
          if (col < HIDN && k0 < HIDN) {    // 200 % 8 == 0: frag all-valid or all-zero
            const float* wp = We2 + (size_t)col * HIDN + k0;
            *(float4*)(vv)     = *(const float4*)(wp);
            *(float4*)(vv + 4) = *(const float4*)(wp + 4);
          } else {
#pragma unroll
            for (int j = 0; j < 8; ++j) vv[j] = 0.f;
          }
          short8_t Bh, Bl;
          build_hilo8(vv, Bh, Bl);
          acc = MFMA_BF16(Ah[kf], Bh, acc);
          acc = MFMA_BF16(Al[kf], Bh, acc);
          acc = MFMA_BF16(Ah[kf], Bl, acc);
        }
        const float bv = (col < HIDN) ? be2[col] : 0.f;
#pragma unroll
        for (int r = 0; r < 4; ++r)
          bufA[(lg << 2) + r][col] = fmaxf(acc[r] + bv, 0.f);
      }
    }
    __syncthreads();

    // ---------- layer 3: [16x224] x We3[128x200] -> hz (no relu) ----------
    {
      short8_t Ah[7], Al[7];
#pragma unroll
      for (int kf = 0; kf < 7; ++kf) {
        float vv[8];
        const float* ap = &bufA[lr][(kf << 5) + kbase];
        *(float4*)(vv)     = *(const float4*)(ap);
        *(float4*)(vv + 4) = *(const float4*)(ap + 4);
        build_hilo8(vv, Ah[kf], Al[kf]);
      }
      const int col = (w << 4) + lr;    // 8 n-tiles, one per wave
      f32x4 acc = {0.f, 0.f, 0.f, 0.f};
#pragma unroll
      for (int kf = 0; kf < 7; ++kf) {
        const int k0 = (kf << 5) + kbase;
        float vv[8];
        if (k0 < HIDN) {
          const float* wp = We3 + (size_t)col * HIDN + k0;
          *(float4*)(vv)     = *(const float4*)(wp);
          *(float4*)(vv + 4) = *(const float4*)(wp + 4);
        } else {
#pragma unroll
          for (int j = 0; j < 8; ++j) vv[j] = 0.f;
        }
        short8_t Bh, Bl;
        build_hilo8(vv, Bh, Bl);
        acc = MFMA_BF16(Ah[kf], Bh, acc);
        acc = MFMA_BF16(Al[kf], Bh, acc);
        acc = MFMA_BF16(Ah[kf], Bl, acc);
      }
      const float bv = be3[col];
#pragma unroll
      for (int r = 0; r < 4; ++r)
        hz[(size_t)(b0 + (lg << 2) + r) * LAT + col] = acc[r] + bv;
    }
    return;
  }

  // ================= streaming pack (grid-stride, no LDS) =================
  const int tid = (blockIdx.x - ENC_NB) * 512 + t;
  const int NT  = PACK_NB * 512;

  // G chunks: 4 lanes cover 128B of one WA/WB row (coalesced), writes dwordx4
  short8_t* __restrict__ G8 = (short8_t*)GtU;
  for (int g = tid; g < JPD * 4096; g += NT) {
    const int jp = g >> 12, c = g & 4095;
    const int l = c & 63, spl = (c >> 6) & 1, n = (c >> 7) & 7, ksq = (c >> 10) & 3;
    const int icol = (n << 4) + (l & 15);
    const int k0 = (ksq << 5) + ((l >> 4) << 3);
    const float* __restrict__ src = (jp < LAT)
        ? WA + ((size_t)(icol * LAT + jp)) * 128 + k0
        : WB + ((size_t)(icol * UD + (jp - LAT))) * 128 + k0;
    float vv[8];
    *(float4*)(vv)     = *(const float4*)(src);
    *(float4*)(vv + 4) = *(const float4*)(src + 4);
    FragU fr;
    if (spl == 0) {
#pragma unroll
      for (int j = 0; j < 8; ++j) fr.u[j] = bf16_hi(vv[j]);
    } else {
#pragma unroll
      for (int j = 0; j < 8; ++j) fr.u[j] = bf16_lo(vv[j]);
    }
    G8[g] = fr.s;                       // g == jp*4096 + c
  }
  // Gb
  for (int g = tid; g < JPD * LAT; g += NT) {
    const int jp = g >> 7, i = g & 127;
    Gb[g] = (jp < LAT) ? bA[i * LAT + jp] : bB[i * UD + (jp - LAT)];
  }
  // WH1P: K padded 152->160
  for (int g = tid; g < 16 * 2560; g += NT) {
    const int h = g / 2560, c = g - h * 2560;
    const int l = c & 63, spl = (c >> 6) & 1, nt = (c >> 7) & 3, ks = c >> 9;
    const int col = (nt << 4) + (l & 15);
    const int k0 = (ks << 5) + ((l >> 4) << 3);
    const float* __restrict__ wr = Wh1 + ((size_t)h * 64 + col) * ZUD;
    FragU fr;
#pragma unroll
    for (int j = 0; j < 8; ++j) {
      const int k = k0 + j;
      const float v = (k < ZUD) ? wr[k] : 0.f;
      fr.u[j] = spl ? bf16_lo(v) : bf16_hi(v);
    }
    WH1P[g] = fr.s;
  }
  // WH2P: K=64
  for (int g = tid; g < 16 * 1024; g += NT) {
    const int h = g >> 10, c = g & 1023;
    const int l = c & 63, spl = (c >> 6) & 1, nt = (c >> 7) & 3, ks = (c >> 9) & 1;
    const int col = (nt << 4) + (l & 15);
    const int k0 = (ks << 5) + ((l >> 4) << 3);
    const float* __restrict__ wr = Wh2 + ((size_t)h * 64 + col) * 64 + k0;
    FragU fr;
#pragma unroll
    for (int j = 0; j < 8; ++j) {
      const float v = wr[j];
      fr.u[j] = spl ? bf16_lo(v) : bf16_hi(v);
    }
    WH2P[g] = fr.s;
  }
  // WH3P: K=64, cols>=2 zero
  for (int g = tid; g < 16 * 256; g += NT) {
    const int h = g >> 8, c = g & 255;
    const int l = c & 63, spl = (c >> 6) & 1, ks = (c >> 7) & 1;
    const int col = l & 15;
    const int k0 = (ks << 5) + ((l >> 4) << 3);
    FragU fr;
#pragma unroll
    for (int j = 0; j < 8; ++j) {
      const float v = (col < 2) ? Wh3[((size_t)h * 2 + col) * 64 + k0 + j] : 0.f;
      fr.u[j] = spl ? bf16_lo(v) : bf16_hi(v);
    }
    WH3P[g] = fr.s;
  }
}

// ---------- kernel 2: MFMA transition GEMM (unchanged) ----------
#define GBODY(JP, B00, B01, B10, B11, NJP)                                      \
  {                                                                             \
    const int jp_ = (JP);                                                       \
    const float w0_ = wtile[(rw << 5) + lr][jp_];                               \
    const float w1_ = wtile[(rw << 5) + 16 + lr][jp_];                          \
    Frag2 p0_, p1_;                                                             \
    _Pragma("unroll")                                                           \
    for (int jq = 0; jq < 4; ++jq) {                                            \
      p0_.h2[jq] = __float22bfloat162_rn(                                       \
          make_float2(w0_ * hzr0[2 * jq], w0_ * hzr0[2 * jq + 1]));             \
      p1_.h2[jq] = __float22bfloat162_rn(                                       \
          make_float2(w1_ * hzr1[2 * jq], w1_ * hzr1[2 * jq + 1]));             \
    }                                                                           \
    acc00 = MFMA_BF16(p0_.s, B00, acc00);                                       \
    acc00 = MFMA_BF16(p0_.s, B01, acc00);                                       \
    acc01 = MFMA_BF16(p0_.s, B10, acc01);                                       \
    acc01 = MFMA_BF16(p0_.s, B11, acc01);                                       \
    acc10 = MFMA_BF16(p1_.s, B00, acc10);                                       \
    acc10 = MFMA_BF16(p1_.s, B01, acc10);                                       \
    acc11 = MFMA_BF16(p1_.s, B10, acc11);                                       \
    acc11 = MFMA_BF16(p1_.s, B11, acc11);                                       \
    const size_t nb_ = (size_t)(NJP) * 4096;                                    \
    B00 = G8[nb_ + c00]; B01 = G8[nb_ + c01];                                   \
    B10 = G8[nb_ + c10]; B11 = G8[nb_ + c11];                                   \
  }

__global__ __launch_bounds__(512, 4)
void gemm_mfma_kernel(const float* __restrict__ zt, const float* __restrict__ dt,
                      const float* __restrict__ ut,
                      const unsigned short* __restrict__ GtU,
                      const float* __restrict__ Gb,
                      const float* __restrict__ hz, float* __restrict__ part) {
  __shared__ float wtile[64][156];
  const int t  = threadIdx.x;
  const int l  = t & 63;
  const int w  = t >> 6;
  const int rw = w & 1, cw = w >> 1;
  const int bid   = blockIdx.x;
  const int combo = bid & 7;
  const int ks    = combo & 3;
  const int jph   = combo >> 2;
  const int b0    = (bid >> 3) << 6;
  const int lr  = l & 15, lg = l >> 4;
  const int j0  = jph * 76;

  for (int idx = t; idx < 2048; idx += 512) {
    const int r = idx >> 5, c4 = (idx & 31) << 2;
    *(float4*)(&wtile[r][c4]) = *(const float4*)(zt + (((size_t)(b0 + r)) << 7) + c4);
  }
  for (int idx = t; idx < 384; idx += 512) {
    const int r = idx / 6, u4 = (idx - r * 6) << 2;
    float4 v = *(const float4*)(ut + (size_t)(b0 + r) * UD + u4);
    const float s = dt[b0 + r];
    v.x *= s; v.y *= s; v.z *= s; v.w *= s;
    *(float4*)(&wtile[r][LAT + u4]) = v;
  }
  __syncthreads();

  const int kk = (ks << 5) + (lg << 3);
  float hzr0[8], hzr1[8];
  {
    const float* __restrict__ hp0 = hz + (((size_t)(b0 + (rw << 5) + lr)) << 7) + kk;
    const float* __restrict__ hp1 = hz + (((size_t)(b0 + (rw << 5) + 16 + lr)) << 7) + kk;
    const float4 a0 = *(const float4*)hp0, b0v = *(const float4*)(hp0 + 4);
    const float4 a1 = *(const float4*)hp1, b1v = *(const float4*)(hp1 + 4);
    hzr0[0]=a0.x; hzr0[1]=a0.y; hzr0[2]=a0.z; hzr0[3]=a0.w;
    hzr0[4]=b0v.x; hzr0[5]=b0v.y; hzr0[6]=b0v.z; hzr0[7]=b0v.w;
    hzr1[0]=a1.x; hzr1[1]=a1.y; hzr1[2]=a1.z; hzr1[3]=a1.w;
    hzr1[4]=b1v.x; hzr1[5]=b1v.y; hzr1[6]=b1v.z; hzr1[7]=b1v.w;
  }

  const short8_t* __restrict__ G8 = (const short8_t*)GtU;
  const int n0 = (cw << 1), n1 = (cw << 1) + 1;
  const int c00 = ((((ks << 3) + n0) << 1) + 0) * 64 + l;
  const int c01 = ((((ks << 3) + n0) << 1) + 1) * 64 + l;
  const int c10 = ((((ks << 3) + n1) << 1) + 0) * 64 + l;
  const int c11 = ((((ks << 3) + n1) << 1) + 1) * 64 + l;

  f32x4 acc00 = {0.f,0.f,0.f,0.f}, acc01 = {0.f,0.f,0.f,0.f};
  f32x4 acc10 = {0.f,0.f,0.f,0.f}, acc11 = {0.f,0.f,0.f,0.f};

  short8_t A0 = G8[(size_t)(j0+0)*4096 + c00], A1 = G8[(size_t)(j0+0)*4096 + c01],
           A2 = G8[(size_t)(j0+0)*4096 + c10], A3 = G8[(size_t)(j0+0)*4096 + c11];
  short8_t Bv0 = G8[(size_t)(j0+1)*4096 + c00], Bv1 = G8[(size_t)(j0+1)*4096 + c01],
           Bv2 = G8[(size_t)(j0+1)*4096 + c10], Bv3 = G8[(size_t)(j0+1)*4096 + c11];
  short8_t C0 = G8[(size_t)(j0+2)*4096 + c00], C1 = G8[(size_t)(j0+2)*4096 + c01],
           C2 = G8[(size_t)(j0+2)*4096 + c10], C3 = G8[(size_t)(j0+2)*4096 + c11];
  short8_t D0 = G8[(size_t)(j0+3)*4096 + c00], D1 = G8[(size_t)(j0+3)*4096 + c01],
           D2 = G8[(size_t)(j0+3)*4096 + c10], D3 = G8[(size_t)(j0+3)*4096 + c11];

  const int jend = j0 + 76;
  for (int jp = j0; jp < jend; jp += 4) {
    const int n4 = (jp + 4 < jend) ? jp + 4 : jend - 1;
    const int n5 = (jp + 5 < jend) ? jp + 5 : jend - 1;
    const int n6 = (jp + 6 < jend) ? jp + 6 : jend - 1;
    const int n7 = (jp + 7 < jend) ? jp + 7 : jend - 1;
    GBODY(jp + 0, A0, A1, A2, A3, n4);
    GBODY(jp + 1, Bv0, Bv1, Bv2, Bv3, n5);
    GBODY(jp + 2, C0, C1, C2, C3, n6);
    GBODY(jp + 3, D0, D1, D2, D3, n7);
  }

  {
    const int jb0 = combo * 19;
    for (int jp = jb0; jp < jb0 + 19; ++jp) {
      const float gb0 = Gb[(jp << 7) + (cw << 5) + lr];
      const float gb1 = Gb[(jp << 7) + (cw << 5) + 16 + lr];
#pragma unroll
      for (int r = 0; r < 4; ++r) {
        const float wv0 = wtile[(rw << 5) + (lg << 2) + r][jp];
        const float wv1 = wtile[(rw << 5) + 16 + (lg << 2) + r][jp];
        acc00[r] += wv0 * gb0; acc01[r] += wv0 * gb1;
        acc10[r] += wv1 * gb0; acc11[r] += wv1 * gb1;
      }
    }
  }

  float* __restrict__ dst = part + (size_t)combo * PART_STRIDE + (((size_t)b0) << 7);
  const int colb = (cw << 5) + lr;
#pragma unroll
  for (int r = 0; r < 4; ++r) {
    const int row0 = (rw << 5) + (lg << 2) + r;
    const int row1 = row0 + 16;
    dst[((size_t)row0 << 7) + colb]      = acc00[r];
    dst[((size_t)row0 << 7) + colb + 16] = acc01[r];
    dst[((size_t)row1 << 7) + colb]      = acc10[r];
    dst[((size_t)row1 << 7) + colb + 16] = acc11[r];
  }
}

// ---------- kernel 3: MFMA heads (unchanged) ----------
__global__ __launch_bounds__(512, 4)
void heads_kernel(const float* __restrict__ ut, const float* __restrict__ part,
                  const short8_t* __restrict__ WH1P, const float* __restrict__ bh1,
                  const short8_t* __restrict__ WH2P, const float* __restrict__ bh2,
                  const short8_t* __restrict__ WH3P, const float* __restrict__ bh3,
                  const float* __restrict__ Wi, const float* __restrict__ bi,
                  float* __restrict__ out) {
  __shared__ float    zuf[64][156];
  __shared__ short8_t g1a[1024];
  __shared__ short8_t g2a[1024];
  const int t  = threadIdx.x;
  const int l  = t & 63;
  const int w  = t >> 6;
  const int wm = w >> 1, wn = w & 1;
  const int mb = blockIdx.x >> 2;
  const int hg = blockIdx.x & 3;
  const int b0 = mb << 6;
  float* __restrict__ zt1_out = out;
  float* __restrict__ yt1_out = out + (size_t)NB * LAT;

  for (int idx = t; idx < 2048; idx += 512) {
    const int r = idx >> 5, c4 = (idx & 31) << 2;
    const size_t off = (((size_t)(b0 + r)) << 7) + c4;
    float4 s = *(const float4*)(part + off);
#pragma unroll
    for (int q = 1; q < 8; ++q) {
      const float4 v = *(const float4*)(part + (size_t)q * PART_STRIDE + off);
      s.x += v.x; s.y += v.y; s.z += v.z; s.w += v.w;
    }
    *(float4*)(&zuf[r][c4]) = s;
    if (hg == 0) *(float4*)(zt1_out + off) = s;
  }
  for (int idx = t; idx < 384; idx += 512) {
    const int r = idx / 6, u4 = (idx - r * 6) << 2;
    *(float4*)(&zuf[r][LAT + u4]) = *(const float4*)(ut + (size_t)(b0 + r) * UD + u4);
  }
  __syncthreads();

  short8_t Ahi[5], Alo[5];
  {
    const int arow = (wm << 4) + (l & 15);
#pragma unroll
    for (int ks = 0; ks < 5; ++ks) {
      const int k0 = (ks << 5) + ((l >> 4) << 3);
      FragU fh, fl;
      if (k0 < ZUD) {
        const float4 va = *(const float4*)(&zuf[arow][k0]);
        const float4 vb = *(const float4*)(&zuf[arow][k0 + 4]);
        const float vv[8] = {va.x, va.y, va.z, va.w, vb.x, vb.y, vb.z, vb.w};
#pragma unroll
        for (int j = 0; j < 8; ++j) { fh.u[j] = bf16_hi(vv[j]); fl.u[j] = bf16_lo(vv[j]); }
      } else {
#pragma unroll
        for (int j = 0; j < 8; ++j) { fh.u[j] = 0; fl.u[j] = 0; }
      }
      Ahi[ks] = fh.s; Alo[ks] = fl.s;
    }
  }

  unsigned short* __restrict__ g1s = (unsigned short*)g1a;
  unsigned short* __restrict__ g2s = (unsigned short*)g2a;
  const int lq = l >> 4;

  for (int hc = 0; hc < 4; ++hc) {
    const int hh = (hg << 2) + hc;

    const short8_t* __restrict__ W1 = WH1P + (size_t)hh * 2560;
    short8_t b1h[5][2], b1l[5][2];
#pragma unroll
    for (int ks = 0; ks < 5; ++ks)
#pragma unroll
      for (int nt = 0; nt < 2; ++nt) {
        const int ntg = (wn << 1) + nt;
        b1h[ks][nt] = W1[(((ks << 2) + ntg) * 2 + 0) * 64 + l];
        b1l[ks][nt] = W1[(((ks << 2) + ntg) * 2 + 1) * 64 + l];
      }
    f32x4 a1[2] = {{0.f,0.f,0.f,0.f},{0.f,0.f,0.f,0.f}};
#pragma unroll
    for (int ks = 0; ks < 5; ++ks)
#pragma unroll
      for (int nt = 0; nt < 2; ++nt) {
        a1[nt] = MFMA_BF16(Ahi[ks], b1h[ks][nt], a1[nt]);
        a1[nt] = MFMA_BF16(Alo[ks], b1h[ks][nt], a1[nt]);
        a1[nt] = MFMA_BF16(Ahi[ks], b1l[ks][nt], a1[nt]);
      }
#pragma unroll
    for (int nt = 0; nt < 2; ++nt) {
      const int C = (wn << 5) + (nt << 4) + (l & 15);
      const float bv = bh1[(hh << 6) + C];
      const int chunkbase = (((wm << 1) + (C >> 5)) << 1);
#pragma unroll
      for (int r = 0; r < 4; ++r) {
        const float v = fmaxf(a1[nt][r] + bv, 0.f);
        const int lane2 = ((lq << 2) + r) | ((((C >> 3) & 3)) << 4);
        g1s[(((chunkbase + 0) * 64 + lane2) << 3) + (C & 7)] = bf16_hi(v);
        g1s[(((chunkbase + 1) * 64 + lane2) << 3) + (C & 7)] = bf16_lo(v);
      }
    }
    __syncthreads();

    const short8_t* __restrict__ W2 = WH2P + (size_t)hh * 1024;
    short8_t A2h[2], A2l[2];
#pragma unroll
    for (int ks = 0; ks < 2; ++ks) {
      A2h[ks] = g1a[(((wm << 1) + ks) * 2 + 0) * 64 + l];
      A2l[ks] = g1a[(((wm << 1) + ks) * 2 + 1) * 64 + l];
    }
    f32x4 a2[2] = {{0.f,0.f,0.f,0.f},{0.f,0.f,0.f,0.f}};
#pragma unroll
    for (int ks = 0; ks < 2; ++ks)
#pragma unroll
      for (int nt = 0; nt < 2; ++nt) {
        const int ntg = (wn << 1) + nt;
        const short8_t bh = W2[(((ks << 2) + ntg) * 2 + 0) * 64 + l];
        const short8_t bl = W2[(((ks << 2) + ntg) * 2 + 1) * 64 + l];
        a2[nt] = MFMA_BF16(A2h[ks], bh, a2[nt]);
        a2[nt] = MFMA_BF16(A2l[ks], bh, a2[nt]);
        a2[nt] = MFMA_BF16(A2h[ks], bl, a2[nt]);
      }
#pragma unroll
    for (int nt = 0; nt < 2; ++nt) {
      const int C = (wn << 5) + (nt << 4) + (l & 15);
      const float bv = bh2[(hh << 6) + C];
      const int chunkbase = (((wm << 1) + (C >> 5)) << 1);
#pragma unroll
      for (int r = 0; r < 4; ++r) {
        const float v = fmaxf(a2[nt][r] + bv, 0.f);
        const int lane2 = ((lq << 2) + r) | ((((C >> 3) & 3)) << 4);
        g2s[(((chunkbase + 0) * 64 + lane2) << 3) + (C & 7)] = bf16_hi(v);
        g2s[(((chunkbase + 1) * 64 + lane2) << 3) + (C & 7)] = bf16_lo(v);
      }
    }
    __syncthreads();

    if (wn == 0) {
      const short8_t* __restrict__ W3 = WH3P + (size_t)hh * 256;
      f32x4 a3 = {0.f,0.f,0.f,0.f};
#pragma unroll
      for (int ks = 0; ks < 2; ++ks) {
        const short8_t Ah = g2a[(((wm << 1) + ks) * 2 + 0) * 64 + l];
        const short8_t Al = g2a[(((wm << 1) + ks) * 2 + 1) * 64 + l];
        const short8_t bh = W3[((ks << 1) + 0) * 64 + l];
        const short8_t bl = W3[((ks << 1) + 1) * 64 + l];
        a3 = MFMA_BF16(Ah, bh, a3);
        a3 = MFMA_BF16(Al, bh, a3);
        a3 = MFMA_BF16(Ah, bl, a3);
      }
      if ((l & 15) < 2) {
        const int col = l & 15;
        const float bv = bh3[(hh << 1) + col];
#pragma unroll
        for (int r = 0; r < 4; ++r) {
          const int R = (wm << 4) + (lq << 2) + r;
          yt1_out[(size_t)(b0 + R) * 40 + (hh << 1) + col] = a3[r] + bv;
        }
      }
    }
  }

  if (hg == 3) {
    const int r  = t >> 3, io = t & 7;
    const float4* __restrict__ wrow = (const float4*)(Wi + (size_t)io * ZUD);
    const float4* __restrict__ zr   = (const float4*)(&zuf[r][0]);
    float a0 = 0, a1 = 0, a2 = 0, a3 = 0;
#pragma unroll
    for (int cc = 0; cc < 38; ++cc) {
      const float4 wv = wrow[cc];
      const float4 zv = zr[cc];
      a0 = fmaf(wv.x, zv.x, a0); a1 = fmaf(wv.y, zv.y, a1);
      a2 = fmaf(wv.z, zv.z, a2); a3 = fmaf(wv.w, zv.w, a3);
    }
    yt1_out[(size_t)(b0 + r) * 40 + 32 + io] = a0 + a1 + a2 + a3 + bi[io];
  }
}

// ---------------------------------------------------------------------------
extern "C" void kernel_launch(void* const* d_in, const int* in_sizes, int n_in,
                              void* d_out, int out_size, void* d_ws, size_t ws_size,
                              hipStream_t stream) {
  const float* zt  = (const float*)d_in[0];
  const float* dt  = (const float*)d_in[1];
  const float* ut  = (const float*)d_in[2];
  const float* We1 = (const float*)d_in[3];
  const float* be1 = (const float*)d_in[4];
  const float* We2 = (const float*)d_in[5];
  const float* be2 = (const float*)d_in[6];
  const float* We3 = (const float*)d_in[7];
  const float* be3 = (const float*)d_in[8];
  const float* WA  = (const float*)d_in[9];
  const float* bA  = (const float*)d_in[10];
  const float* WB  = (const float*)d_in[11];
  const float* bB  = (const float*)d_in[12];
  const float* Wh1 = (const float*)d_in[13];
  const float* bh1 = (const float*)d_in[14];
  const float* Wh2 = (const float*)d_in[15];
  const float* bh2 = (const float*)d_in[16];
  const float* Wh3 = (const float*)d_in[17];
  const float* bh3 = (const float*)d_in[18];
  const float* Wi  = (const float*)d_in[19];
  const float* bi  = (const float*)d_in[20];

  float* ws = (float*)d_ws;
  unsigned short* GtU = (unsigned short*)(ws + GT_OFF);
  float* Gb   = ws + GB_OFF;
  float* hz   = ws + HZ_OFF;
  float* part = ws + PART_OFF;
  short8_t* WH1P = (short8_t*)(ws + WH1P_OFF);
  short8_t* WH2P = (short8_t*)(ws + WH2P_OFF);
  short8_t* WH3P = (short8_t*)(ws + WH3P_OFF);
  float* out  = (float*)d_out;

  hipLaunchKernelGGL(prep_kernel, dim3(ENC_NB + PACK_NB), dim3(512), 0, stream,
                     WA, bA, WB, bB, GtU, Gb,
                     zt, dt, We1, be1, We2, be2, We3, be3, hz,
                     Wh1, Wh2, Wh3, WH1P, WH2P, WH3P);
  hipLaunchKernelGGL(gemm_mfma_kernel, dim3(512), dim3(512), 0, stream,
                     zt, dt, ut, GtU, Gb, hz, part);
  hipLaunchKernelGGL(heads_kernel, dim3(256), dim3(512), 0, stream,
                     ut, part, WH1P, bh1, WH2P, bh2, WH3P, bh3, Wi, bi, out);
}